// Round 1
// baseline (68.169 us; speedup 1.0000x reference)
//
#include <hip/hip_runtime.h>
#include <hip/hip_bf16.h>

// PitchLoss: per-note mean of gen_f0 / t_f0 over [onset_k, offset_k),
// loss = mean( |mean_gen - mean_ref| > 0.5 ).
// T = 32768, N = 1024, seg = 32 (contiguous, non-overlapping tiling).
//
// Design: one block of 1024 threads (16 waves), one thread per note.
// Each thread sums its segment (float4 fast path: segments are 128B-aligned
// and length%4==0 in the given inputs). Flag count via wave ballot+popcount,
// then a tiny LDS reduction; thread 0 writes the scalar loss.

#define THRESHOLD 0.5f

__global__ __launch_bounds__(1024) void pitch_loss_kernel(
    const float* __restrict__ gen,
    const float* __restrict__ tf,
    const int* __restrict__ onset,
    const int* __restrict__ offs,
    float* __restrict__ out,
    int N) {
  const int k = threadIdx.x;

  int flag = 0;
  if (k < N) {
    const int a = onset[k];
    const int b = offs[k];
    const int len = b - a;

    float sg = 0.0f, st = 0.0f;
    if (((a & 3) == 0) && ((len & 3) == 0)) {
      // Vectorized path: 16B-aligned segment, multiple-of-4 length.
      const float4* g4 = reinterpret_cast<const float4*>(gen + a);
      const float4* t4 = reinterpret_cast<const float4*>(tf + a);
      const int n4 = len >> 2;
      for (int i = 0; i < n4; ++i) {
        const float4 g = g4[i];
        const float4 t = t4[i];
        sg += g.x + g.y + g.z + g.w;
        st += t.x + t.y + t.z + t.w;
      }
    } else {
      for (int t = a; t < b; ++t) {
        sg += gen[t];
        st += tf[t];
      }
    }

    const float inv = 1.0f / (float)len;
    const float diff = fabsf(sg * inv - st * inv);
    flag = (diff > THRESHOLD) ? 1 : 0;
  }

  // Per-wave count via 64-bit ballot, then LDS reduce across 16 waves.
  __shared__ int warp_cnt[16];
  const unsigned long long bal = __ballot(flag);
  const int wid = threadIdx.x >> 6;
  const int lane = threadIdx.x & 63;
  if (lane == 0) warp_cnt[wid] = __popcll(bal);
  __syncthreads();

  if (threadIdx.x == 0) {
    int c = 0;
    const int nw = (blockDim.x + 63) >> 6;
    for (int i = 0; i < nw; ++i) c += warp_cnt[i];
    out[0] = (float)c / (float)N;
  }
}

extern "C" void kernel_launch(void* const* d_in, const int* in_sizes, int n_in,
                              void* d_out, int out_size, void* d_ws, size_t ws_size,
                              hipStream_t stream) {
  const float* gen = (const float*)d_in[0];
  const float* tf = (const float*)d_in[1];
  const int* onset = (const int*)d_in[2];
  const int* offs = (const int*)d_in[3];
  float* out = (float*)d_out;
  const int N = in_sizes[2];

  pitch_loss_kernel<<<1, 1024, 0, stream>>>(gen, tf, onset, offs, out, N);
}

// Round 2
// 61.718 us; speedup vs baseline: 1.1045x; 1.1045x over previous
//
#include <hip/hip_runtime.h>
#include <hip/hip_bf16.h>

// PitchLoss: per-note mean of gen_f0 / t_f0 over [onset_k, offset_k),
// loss = mean( |mean_gen - mean_ref| > 0.5 ).
// T = 32768, N = 1024, seg = 32 (contiguous, non-overlapping tiling).
//
// R2 design: spread the 256 KB fetch across CUs. 32 blocks x 256 threads,
// 8 threads per note (one float4 pair per lane), __shfl_xor reduce within
// the 8-lane group. Cross-block scalar output via fenced ticket in d_ws
// (zeroed by an 8-byte hipMemsetAsync) -- 2 enqueues total, 1 kernel.

#define THRESHOLD 0.5f

__global__ __launch_bounds__(256) void pitch_loss_kernel(
    const float* __restrict__ gen,
    const float* __restrict__ tf,
    const int* __restrict__ onset,
    const int* __restrict__ offs,
    int N,
    int* __restrict__ counters,   // [0]=flag count, [1]=ticket
    float* __restrict__ out) {
  const int tid = threadIdx.x;
  const int g = blockIdx.x * blockDim.x + tid;
  const int note = g >> 3;   // 8 threads per note
  const int j = g & 7;

  int flag = 0;
  if (note < N) {
    const int a = onset[note];
    const int b = offs[note];
    const int len = b - a;

    float sg = 0.0f, st = 0.0f;
    if (((a & 3) == 0) && ((len & 3) == 0)) {
      // Vector path: 16B-aligned start, multiple-of-4 length.
      for (int idx = a + (j << 2); idx + 3 < b; idx += 32) {
        const float4 gv = *reinterpret_cast<const float4*>(gen + idx);
        const float4 tv = *reinterpret_cast<const float4*>(tf + idx);
        sg += gv.x + gv.y + gv.z + gv.w;
        st += tv.x + tv.y + tv.z + tv.w;
      }
    } else {
      for (int idx = a + j; idx < b; idx += 8) {
        sg += gen[idx];
        st += tf[idx];
      }
    }

    // Sum across the 8-lane group (groups never straddle a wave).
    for (int d = 1; d < 8; d <<= 1) {
      sg += __shfl_xor(sg, d, 64);
      st += __shfl_xor(st, d, 64);
    }

    if (j == 0) {
      const float inv = 1.0f / (float)len;
      const float diff = fabsf(sg * inv - st * inv);
      flag = (diff > THRESHOLD) ? 1 : 0;
    }
  }

  // Per-wave count (flags live only on lanes where j==0), then LDS reduce.
  __shared__ int warp_cnt[4];
  const unsigned long long bal = __ballot(flag);
  const int wid = tid >> 6;
  const int lane = tid & 63;
  if (lane == 0) warp_cnt[wid] = __popcll(bal);
  __syncthreads();

  if (tid == 0) {
    int c = warp_cnt[0];
    const int nw = (blockDim.x + 63) >> 6;
    for (int i = 1; i < nw; ++i) c += warp_cnt[i];
    atomicAdd(&counters[0], c);
    __threadfence();  // make the count add visible before taking a ticket
    const int t = atomicAdd(&counters[1], 1);
    if (t == (int)gridDim.x - 1) {
      // All blocks' adds happened-before their tickets; we hold the last one.
      const int total = atomicAdd(&counters[0], 0);
      out[0] = (float)total / (float)N;
    }
  }
}

extern "C" void kernel_launch(void* const* d_in, const int* in_sizes, int n_in,
                              void* d_out, int out_size, void* d_ws, size_t ws_size,
                              hipStream_t stream) {
  const float* gen = (const float*)d_in[0];
  const float* tf = (const float*)d_in[1];
  const int* onset = (const int*)d_in[2];
  const int* offs = (const int*)d_in[3];
  float* out = (float*)d_out;
  const int N = in_sizes[2];

  int* counters = (int*)d_ws;
  hipMemsetAsync(counters, 0, 2 * sizeof(int), stream);

  const int threads_needed = N * 8;
  const int block = 256;
  const int grid = (threads_needed + block - 1) / block;
  pitch_loss_kernel<<<grid, block, 0, stream>>>(gen, tf, onset, offs, N,
                                                counters, out);
}

// Round 3
// 60.859 us; speedup vs baseline: 1.1201x; 1.0141x over previous
//
#include <hip/hip_runtime.h>
#include <hip/hip_bf16.h>

// PitchLoss: per-note mean of gen_f0 / t_f0 over [onset_k, offset_k),
// loss = mean( |mean_gen - mean_ref| > 0.5 ).
// T = 32768, N = 1024, seg = 32 (contiguous, non-overlapping tiling).
//
// R3 design: ONE graph node. 64 blocks x 64 threads (1 wave/block),
// 4 threads per note. Cross-block reduce without any pre-zeroed memory:
// each block atomicExch-publishes (0x5A5A0000 | count) into ws[bid];
// block 0's wave spin-gathers all partials in parallel (tag check rejects
// both the 0xAA harness poison and fresh-alloc zeros), shuffle-reduces,
// and writes the scalar loss. Producers never wait -> deadlock-free.

#define THRESHOLD 0.5f

__global__ __launch_bounds__(64) void pitch_loss_kernel(
    const float* __restrict__ gen,
    const float* __restrict__ tf,
    const int* __restrict__ onset,
    const int* __restrict__ offs,
    int N,
    int nblocks,
    int* __restrict__ ws_partials,
    float* __restrict__ out) {
  const int lane = threadIdx.x;            // 64 threads = 1 wave
  const int g = blockIdx.x * 64 + lane;
  const int note = g >> 2;                 // 4 threads per note
  const int j = g & 3;

  int flag = 0;
  if (note < N) {
    const int a = onset[note];
    const int b = offs[note];
    const int len = b - a;

    float sg = 0.0f, st = 0.0f;
    if (((a & 3) == 0) && ((len & 3) == 0)) {
      // Vector path: thread j takes float4-chunks j, j+4, j+8, ...
      for (int c = j; (c << 2) < len; c += 4) {
        const float4 gv = *reinterpret_cast<const float4*>(gen + a + (c << 2));
        const float4 tv = *reinterpret_cast<const float4*>(tf + a + (c << 2));
        sg += gv.x + gv.y + gv.z + gv.w;
        st += tv.x + tv.y + tv.z + tv.w;
      }
    } else {
      for (int idx = a + j; idx < b; idx += 4) {
        sg += gen[idx];
        st += tf[idx];
      }
    }

    // Sum across the 4-lane group.
    sg += __shfl_xor(sg, 1, 64); st += __shfl_xor(st, 1, 64);
    sg += __shfl_xor(sg, 2, 64); st += __shfl_xor(st, 2, 64);

    if (j == 0) {
      const float inv = 1.0f / (float)len;
      const float diff = fabsf(sg * inv - st * inv);
      flag = (diff > THRESHOLD) ? 1 : 0;
    }
  }

  // Per-block count via ballot (flags sit on j==0 lanes), publish with tag.
  const unsigned long long bal = __ballot(flag);
  if (lane == 0) {
    const int c = __popcll(bal);
    atomicExch(&ws_partials[blockIdx.x], 0x5A5A0000 | c);
  }

  // Block 0: parallel spin-gather of all partials, wave-reduce, write loss.
  if (blockIdx.x == 0) {
    int cnt = 0;
    for (int i = lane; i < nblocks; i += 64) {
      int v;
      do {
        v = atomicAdd(&ws_partials[i], 0);
      } while ((v >> 16) != 0x5A5A);
      cnt += v & 0xFFFF;
    }
    for (int d = 1; d < 64; d <<= 1) cnt += __shfl_xor(cnt, d, 64);
    if (lane == 0) out[0] = (float)cnt / (float)N;
  }
}

extern "C" void kernel_launch(void* const* d_in, const int* in_sizes, int n_in,
                              void* d_out, int out_size, void* d_ws, size_t ws_size,
                              hipStream_t stream) {
  const float* gen = (const float*)d_in[0];
  const float* tf = (const float*)d_in[1];
  const int* onset = (const int*)d_in[2];
  const int* offs = (const int*)d_in[3];
  float* out = (float*)d_out;
  const int N = in_sizes[2];

  int* partials = (int*)d_ws;
  const int threads_needed = N * 4;        // 4 threads per note
  const int block = 64;
  const int grid = (threads_needed + block - 1) / block;

  pitch_loss_kernel<<<grid, block, 0, stream>>>(gen, tf, onset, offs, N, grid,
                                                partials, out);
}